// Round 1
// baseline (99.148 us; speedup 1.0000x reference)
//
#include <hip/hip_runtime.h>
#include <hip/hip_bf16.h>

// Problem: B=8, N=2048, H=256, HEADS=4, hd=64, BNECK=8 (TB=24, 3H=768)
// Key insight: attn_reg_loss = exp(log_w) * mean(|softmax(...)|) = exp(log_w)/N
// exactly (softmax rows sum to 1, entries >= 0), so the entire [8,4,2048,2048]
// softmax path (and gu/gv) is dead. Only the linear-attention path is computed.
//
// ws layout (floats):
//   t1  : [16384][24]            393216
//   z   : [8][4][2048]            65536
//   kvp : [8][4][8][64][64]     1048576   (8 partials per (b,h))
//   kv  : [8][4][64][64]         131072
// total 1,638,400 floats = 6.55 MB

#define OFF_T1  0
#define OFF_Z   393216
#define OFF_KVP 458752
#define OFF_KV  4653056

__device__ __forceinline__ float lanebc(float v, int l) {
    return __uint_as_float(__builtin_amdgcn_readlane(__float_as_uint(v), (unsigned)l));
}

// ---------------------------------------------------------------------------
// K1: t1 = x @ Wq1 + bq1   ([16384 x 256] * [256 x 24])
// grid 256 blocks x 128 threads, 64 rows/block.
// LDS tiles padded to 260 floats/row: 4-row / 3-j register blocking, rows and
// j interleaved (r = rgrp + 16*rr, j = jgrp + 8*jj) so concurrent b128 reads
// hit distinct banks.
// ---------------------------------------------------------------------------
__global__ __launch_bounds__(128) void k1_t1(
    const float* __restrict__ x, const float* __restrict__ Wq1,
    const float* __restrict__ bq1, const float* __restrict__ logw,
    float* __restrict__ t1g, float* __restrict__ loss_out)
{
    __shared__ float xs[64][260];
    __shared__ float w1t[24][260];
    const int t = threadIdx.x;
    const long row0 = (long)blockIdx.x * 64;

    // stage x rows (64x256) via float4
    {
        const float4* xg4 = reinterpret_cast<const float4*>(x + row0 * 256);
        for (int i = t; i < 4096; i += 128) {
            float4 v4 = xg4[i];
            int r = i >> 6, c4 = (i & 63) << 2;
            xs[r][c4 + 0] = v4.x; xs[r][c4 + 1] = v4.y;
            xs[r][c4 + 2] = v4.z; xs[r][c4 + 3] = v4.w;
        }
    }
    // stage Wq1 transposed: w1t[j][i] = Wq1[i*24+j]
    for (int i = t; i < 6144; i += 128) {
        int ii = i / 24, j = i - ii * 24;
        w1t[j][ii] = Wq1[i];
    }
    __syncthreads();

    const int rgrp = t >> 3;      // 0..15
    const int jgrp = t & 7;       // 0..7
    float acc[4][3] = {};
    for (int i4 = 0; i4 < 64; ++i4) {
        float4 xa[4], wb[3];
        #pragma unroll
        for (int rr = 0; rr < 4; ++rr)
            xa[rr] = *reinterpret_cast<const float4*>(&xs[rgrp + 16 * rr][i4 << 2]);
        #pragma unroll
        for (int jj = 0; jj < 3; ++jj)
            wb[jj] = *reinterpret_cast<const float4*>(&w1t[jgrp + 8 * jj][i4 << 2]);
        #pragma unroll
        for (int rr = 0; rr < 4; ++rr) {
            #pragma unroll
            for (int jj = 0; jj < 3; ++jj) {
                acc[rr][jj] = fmaf(xa[rr].x, wb[jj].x, acc[rr][jj]);
                acc[rr][jj] = fmaf(xa[rr].y, wb[jj].y, acc[rr][jj]);
                acc[rr][jj] = fmaf(xa[rr].z, wb[jj].z, acc[rr][jj]);
                acc[rr][jj] = fmaf(xa[rr].w, wb[jj].w, acc[rr][jj]);
            }
        }
    }
    #pragma unroll
    for (int rr = 0; rr < 4; ++rr) {
        #pragma unroll
        for (int jj = 0; jj < 3; ++jj) {
            const int j = jgrp + 8 * jj;
            t1g[(row0 + rgrp + 16 * rr) * 24 + j] = acc[rr][jj] + bq1[j];
        }
    }

    // loss = exp(log_w)/N (exact collapse of the softmax reg term)
    if (blockIdx.x == 0 && t == 0)
        loss_out[0] = expf(logw[0]) * (1.0f / 2048.0f);
}

// ---------------------------------------------------------------------------
// K2: per (b, h, chunk of 256 rows): regenerate kf/v from t1, accumulate
// kv-partial (64x64) with per-wave 8x8 register tiles; also z = 1/(sum_d kf).
// grid 256 blocks (b*32 + h*8 + ch) x 256 threads.
// ---------------------------------------------------------------------------
__global__ __launch_bounds__(256) void k2_kv(
    const float* __restrict__ t1g, const float* __restrict__ Wq2,
    const float* __restrict__ bq2, float* __restrict__ kvp,
    float* __restrict__ zg)
{
    __shared__ float kf_c[64][68];
    __shared__ float v_c[64][68];
    __shared__ float merge[4][64][68];
    const int t = threadIdx.x;
    const int bi = blockIdx.x;
    const int b = bi >> 5, h = (bi >> 3) & 3, ch = bi & 7;
    const int c = t & 63, wv = t >> 6;   // column / wave id
    const int lane = c;

    // hoist k/v weight columns (this head, this c) into registers
    float wkr[24], wvr[24];
    #pragma unroll
    for (int j = 0; j < 24; ++j) {
        wkr[j] = Wq2[j * 768 + 256 + h * 64 + c];
        wvr[j] = Wq2[j * 768 + 512 + h * 64 + c];
    }
    const float bk = bq2[256 + h * 64 + c];
    const float bv = bq2[512 + h * 64 + c];

    const int d0 = (lane >> 3) << 3;     // 8x8 output tile per lane
    const int e0 = (lane & 7) << 3;
    float acc[8][8] = {};

    const long rowbase = (long)b * 2048 + (long)ch * 256;
    const long zbase = (((long)b * 4 + h) << 11) + ch * 256;

    for (int sub = 0; sub < 4; ++sub) {
        const long r0row = rowbase + sub * 64;
        // generate kf/v for 64 rows: wave wv handles rows {wv + 4i}
        #pragma unroll
        for (int i = 0; i < 16; ++i) {
            const int r = wv + (i << 2);
            const float* t1row = t1g + (r0row + r) * 24;
            float sk = bk, sv = bv;
            #pragma unroll
            for (int j4 = 0; j4 < 24; j4 += 4) {
                float4 tv = *reinterpret_cast<const float4*>(t1row + j4);
                sk = fmaf(tv.x, wkr[j4 + 0], sk); sv = fmaf(tv.x, wvr[j4 + 0], sv);
                sk = fmaf(tv.y, wkr[j4 + 1], sk); sv = fmaf(tv.y, wvr[j4 + 1], sv);
                sk = fmaf(tv.z, wkr[j4 + 2], sk); sv = fmaf(tv.z, wvr[j4 + 2], sv);
                sk = fmaf(tv.w, wkr[j4 + 3], sk); sv = fmaf(tv.w, wvr[j4 + 3], sv);
            }
            kf_c[r][c] = sk > 0.f ? sk + 1.f : expf(sk);
            v_c[r][c] = sv;
        }
        __syncthreads();
        // z for the 64 rows of this sub: wave 0, one row per lane
        if (wv == 0) {
            float rs = 0.f;
            #pragma unroll
            for (int k = 0; k < 16; ++k) {
                float4 kk = *reinterpret_cast<const float4*>(&kf_c[lane][k << 2]);
                rs += (kk.x + kk.y) + (kk.z + kk.w);
            }
            zg[zbase + sub * 64 + lane] = 1.0f / (rs + 1e-8f);
        }
        // accumulate: wave wv handles n in [wv*16, wv*16+16)
        for (int k = 0; k < 16; ++k) {
            const int n = wv * 16 + k;
            float4 ka0 = *reinterpret_cast<const float4*>(&kf_c[n][d0]);
            float4 ka1 = *reinterpret_cast<const float4*>(&kf_c[n][d0 + 4]);
            float4 va0 = *reinterpret_cast<const float4*>(&v_c[n][e0]);
            float4 va1 = *reinterpret_cast<const float4*>(&v_c[n][e0 + 4]);
            const float ka[8] = {ka0.x, ka0.y, ka0.z, ka0.w, ka1.x, ka1.y, ka1.z, ka1.w};
            const float va[8] = {va0.x, va0.y, va0.z, va0.w, va1.x, va1.y, va1.z, va1.w};
            #pragma unroll
            for (int i = 0; i < 8; ++i) {
                #pragma unroll
                for (int j = 0; j < 8; ++j)
                    acc[i][j] = fmaf(ka[i], va[j], acc[i][j]);
            }
        }
        __syncthreads();
    }

    // merge the 4 per-wave partials inside the block -> one partial per block
    #pragma unroll
    for (int i = 0; i < 8; ++i) {
        *reinterpret_cast<float4*>(&merge[wv][lane][i * 8]) =
            make_float4(acc[i][0], acc[i][1], acc[i][2], acc[i][3]);
        *reinterpret_cast<float4*>(&merge[wv][lane][i * 8 + 4]) =
            make_float4(acc[i][4], acc[i][5], acc[i][6], acc[i][7]);
    }
    __syncthreads();
    float* dst = kvp + (long)bi * 4096;
    for (int oi = t; oi < 4096; oi += 256) {
        const int d = oi >> 6, e = oi & 63;
        const int ln = ((d >> 3) << 3) + (e >> 3);
        const int ix = ((d & 7) << 3) + (e & 7);
        dst[oi] = (merge[0][ln][ix] + merge[1][ln][ix]) +
                  (merge[2][ln][ix] + merge[3][ln][ix]);
    }
}

// ---------------------------------------------------------------------------
// K2b: kv[b,h] = sum over 8 chunk-partials. grid 128 x 256.
// ---------------------------------------------------------------------------
__global__ __launch_bounds__(256) void k2b_red(
    const float* __restrict__ kvp, float* __restrict__ kvg)
{
    const int bid = blockIdx.x;
    const int bh = bid >> 2;
    const int base = (bid & 3) * 1024;
    const int t = threadIdx.x;
    #pragma unroll
    for (int pp = 0; pp < 4; ++pp) {
        const int pos = base + pp * 256 + t;
        float s = 0.f;
        #pragma unroll
        for (int q = 0; q < 8; ++q)
            s += kvp[((long)bh * 8 + q) * 4096 + pos];
        kvg[(long)bh * 4096 + pos] = s;
    }
}

// ---------------------------------------------------------------------------
// K3: out = ((z * (qf @ kv)) @ Wo1 + bo1) @ Wo2 + bo2
// grid 1024 blocks x 256 threads, 16 rows/block. kv column in 64 VGPRs per
// thread; qf broadcast via v_readlane (off the LDS pipe).
// ---------------------------------------------------------------------------
__global__ __launch_bounds__(256) void k3_out(
    const float* __restrict__ t1g, const float* __restrict__ Wq2,
    const float* __restrict__ bq2, const float* __restrict__ zg,
    const float* __restrict__ kvg,
    const float* __restrict__ Wo1, const float* __restrict__ bo1,
    const float* __restrict__ Wo2, const float* __restrict__ bo2,
    float* __restrict__ outg)
{
    __shared__ __align__(16) float ols[256];
    __shared__ __align__(16) float o1s[8];
    const int t = threadIdx.x;
    const long row0 = (long)blockIdx.x * 16;
    const int b = (int)(row0 >> 11);
    const int h = t >> 6, lane = t & 63;
    const int g = t >> 5, l = t & 31;

    // kv column for (h, e=lane) in registers
    float kvcol[64];
    {
        const float* kvb = kvg + (long)b * 16384 + h * 4096 + lane;
        #pragma unroll
        for (int d = 0; d < 64; ++d) kvcol[d] = kvb[d * 64];
    }
    // hoisted weights
    float wq[24];
    #pragma unroll
    for (int j = 0; j < 24; ++j) wq[j] = Wq2[j * 768 + t];
    float wo1r[8];
    #pragma unroll
    for (int i = 0; i < 8; ++i) wo1r[i] = Wo1[(l + (i << 5)) * 8 + g];
    float wo2r[8];
    #pragma unroll
    for (int j = 0; j < 8; ++j) wo2r[j] = Wo2[j * 256 + t];
    const float bq = bq2[t];
    const float bo2t = bo2[t];
    const float bo1g = bo1[g];
    const long zbase = (((long)b * 4 + h) << 11) + (row0 & 2047);

    for (int r = 0; r < 16; ++r) {
        // regenerate qf for column t of this row
        const float* t1row = t1g + (row0 + r) * 24;
        float qraw = bq;
        #pragma unroll
        for (int j4 = 0; j4 < 24; j4 += 4) {
            float4 tv = *reinterpret_cast<const float4*>(t1row + j4);
            qraw = fmaf(tv.x, wq[j4 + 0], qraw);
            qraw = fmaf(tv.y, wq[j4 + 1], qraw);
            qraw = fmaf(tv.z, wq[j4 + 2], qraw);
            qraw = fmaf(tv.w, wq[j4 + 3], qraw);
        }
        const float qf = qraw > 0.f ? qraw + 1.f : expf(qraw);

        // dot over d: qf[h*64+d] lives in lane d of this wave
        float s0 = 0.f, s1 = 0.f, s2 = 0.f, s3 = 0.f;
        #pragma unroll
        for (int d = 0; d < 64; d += 4) {
            s0 = fmaf(lanebc(qf, d + 0), kvcol[d + 0], s0);
            s1 = fmaf(lanebc(qf, d + 1), kvcol[d + 1], s1);
            s2 = fmaf(lanebc(qf, d + 2), kvcol[d + 2], s2);
            s3 = fmaf(lanebc(qf, d + 3), kvcol[d + 3], s3);
        }
        const float zz = zg[zbase + r];
        ols[t] = ((s0 + s1) + (s2 + s3)) * zz;
        __syncthreads();

        // o1[g] = sum_c ols[c]*Wo1[c][g] over 32-lane groups
        float p = 0.f;
        #pragma unroll
        for (int i = 0; i < 8; ++i)
            p = fmaf(ols[l + (i << 5)], wo1r[i], p);
        p += __shfl_xor(p, 16, 64);
        p += __shfl_xor(p, 8, 64);
        p += __shfl_xor(p, 4, 64);
        p += __shfl_xor(p, 2, 64);
        p += __shfl_xor(p, 1, 64);
        if (l == 0) o1s[g] = p + bo1g;
        __syncthreads();

        const float4 o1a = *reinterpret_cast<const float4*>(&o1s[0]);
        const float4 o1b = *reinterpret_cast<const float4*>(&o1s[4]);
        float v = bo2t;
        v = fmaf(o1a.x, wo2r[0], v); v = fmaf(o1a.y, wo2r[1], v);
        v = fmaf(o1a.z, wo2r[2], v); v = fmaf(o1a.w, wo2r[3], v);
        v = fmaf(o1b.x, wo2r[4], v); v = fmaf(o1b.y, wo2r[5], v);
        v = fmaf(o1b.z, wo2r[6], v); v = fmaf(o1b.w, wo2r[7], v);
        outg[(row0 + r) * 256 + t] = v;
        __syncthreads();
    }
}

// ---------------------------------------------------------------------------
extern "C" void kernel_launch(void* const* d_in, const int* in_sizes, int n_in,
                              void* d_out, int out_size, void* d_ws, size_t ws_size,
                              hipStream_t stream)
{
    const float* x    = (const float*)d_in[0];
    const float* Wq1  = (const float*)d_in[1];
    const float* bq1  = (const float*)d_in[2];
    const float* Wq2  = (const float*)d_in[3];
    const float* bq2  = (const float*)d_in[4];
    const float* Wo1  = (const float*)d_in[5];
    const float* bo1  = (const float*)d_in[6];
    const float* Wo2  = (const float*)d_in[7];
    const float* bo2  = (const float*)d_in[8];
    // d_in[9] = gu, d_in[10] = gv : unused (reg-loss collapses analytically)
    const float* logw = (const float*)d_in[11];

    float* out = (float*)d_out;            // [8,2048,256] f32 + loss scalar
    float* ws  = (float*)d_ws;
    float* t1g = ws + OFF_T1;
    float* zg  = ws + OFF_Z;
    float* kvp = ws + OFF_KVP;
    float* kvg = ws + OFF_KV;

    k1_t1<<<256, 128, 0, stream>>>(x, Wq1, bq1, logw, t1g, out + 4194304);
    k2_kv<<<256, 256, 0, stream>>>(t1g, Wq2, bq2, kvp, zg);
    k2b_red<<<128, 256, 0, stream>>>(kvp, kvg);
    k3_out<<<1024, 256, 0, stream>>>(t1g, Wq2, bq2, zg, kvg,
                                     Wo1, bo1, Wo2, bo2, out);
}

// Round 2
// 72.542 us; speedup vs baseline: 1.3668x; 1.3668x over previous
//
#include <hip/hip_runtime.h>
#include <hip/hip_bf16.h>

// B=8, N=2048, H=256, HEADS=4, hd=64, BNECK=8 (TB=24, 3H=768)
// attn_reg_loss = exp(log_w)/N exactly (softmax rows sum to 1) -> gu/gv dead.
// A-trick: out = (z*(qf@kv))@Wo1@Wo2 with A_h = kv_h@Wo1_h precomputed, so kv
// is never materialized; each k2 wave folds its kv-partial into an A-partial.
//
// ws layout (floats):
//   t1 : 0       .. 393216   [16384][24]
//   z  : 393216  .. 458752   [8][4][2048]
//   Ap : 458752  .. 720896   [512 blocks][512]   per-chunk A partials (perm order)
//   A  : 720896  .. 737280   [8][2048]           reduced A (perm order)
//   WT : 737280  .. 743424   [24][256]           Wq1 transposed

#define OFF_T1  0
#define OFF_Z   393216
#define OFF_AP  458752
#define OFF_A   720896
#define OFF_WT  737280

// ---------------------------------------------------------------------------
// K0: transpose Wq1 -> WT[24][256]; write loss scalar.
// ---------------------------------------------------------------------------
__global__ __launch_bounds__(256) void k0_prep(
    const float* __restrict__ Wq1, const float* __restrict__ logw,
    float* __restrict__ WT, float* __restrict__ loss_out)
{
    const int t = threadIdx.x;
    for (int i = t; i < 6144; i += 256) {
        const int r = i / 24, j = i - r * 24;
        WT[j * 256 + r] = Wq1[i];
    }
    if (t == 0) loss_out[0] = __expf(logw[0]) * (1.0f / 2048.0f);
}

// ---------------------------------------------------------------------------
// K1: t1 = x @ Wq1 + bq1   ([16384 x 256] * [256 x 24])
// 256 blocks x 128 threads, 64 rows/block; 4x3 register tile.
// ---------------------------------------------------------------------------
__global__ __launch_bounds__(128) void k1_t1(
    const float* __restrict__ x, const float* __restrict__ WT,
    const float* __restrict__ bq1, float* __restrict__ t1g)
{
    __shared__ float xs[64][260];
    __shared__ float w1t[24][260];
    const int t = threadIdx.x;
    const long row0 = (long)blockIdx.x * 64;

    {   // stage x rows (64x256) via float4
        const float4* xg4 = reinterpret_cast<const float4*>(x + row0 * 256);
        for (int i = t; i < 4096; i += 128) {
            float4 v4 = xg4[i];
            int r = i >> 6, c4 = (i & 63) << 2;
            xs[r][c4 + 0] = v4.x; xs[r][c4 + 1] = v4.y;
            xs[r][c4 + 2] = v4.z; xs[r][c4 + 3] = v4.w;
        }
    }
    {   // stage WT (24x256) via float4 (coalesced; k0 already transposed)
        const float4* wg4 = reinterpret_cast<const float4*>(WT);
        for (int i = t; i < 1536; i += 128) {
            float4 v4 = wg4[i];
            int j = i >> 6, c4 = (i & 63) << 2;
            w1t[j][c4 + 0] = v4.x; w1t[j][c4 + 1] = v4.y;
            w1t[j][c4 + 2] = v4.z; w1t[j][c4 + 3] = v4.w;
        }
    }
    __syncthreads();

    const int rgrp = t >> 3;      // 0..15
    const int jgrp = t & 7;       // 0..7
    float acc[4][3] = {};
    for (int i4 = 0; i4 < 64; ++i4) {
        float4 xa[4], wb[3];
        #pragma unroll
        for (int rr = 0; rr < 4; ++rr)
            xa[rr] = *reinterpret_cast<const float4*>(&xs[rgrp + 16 * rr][i4 << 2]);
        #pragma unroll
        for (int jj = 0; jj < 3; ++jj)
            wb[jj] = *reinterpret_cast<const float4*>(&w1t[jgrp + 8 * jj][i4 << 2]);
        #pragma unroll
        for (int rr = 0; rr < 4; ++rr) {
            #pragma unroll
            for (int jj = 0; jj < 3; ++jj) {
                acc[rr][jj] = fmaf(xa[rr].x, wb[jj].x, acc[rr][jj]);
                acc[rr][jj] = fmaf(xa[rr].y, wb[jj].y, acc[rr][jj]);
                acc[rr][jj] = fmaf(xa[rr].z, wb[jj].z, acc[rr][jj]);
                acc[rr][jj] = fmaf(xa[rr].w, wb[jj].w, acc[rr][jj]);
            }
        }
    }
    #pragma unroll
    for (int rr = 0; rr < 4; ++rr) {
        #pragma unroll
        for (int jj = 0; jj < 3; ++jj) {
            const int j = jgrp + 8 * jj;
            t1g[(row0 + rgrp + 16 * rr) * 24 + j] = acc[rr][jj] + bq1[j];
        }
    }
}

// ---------------------------------------------------------------------------
// K2: per (b, h, chunk of 128 rows): regenerate kf/v from t1, accumulate the
// kv-partial in 8x8 register tiles, fold into A-partial = kvp @ Wo1_h via
// in-register GEMM + e-group shfl butterfly. Also z = 1/(sum_d kf + 1e-8).
// grid 512 blocks (b*64 + h*16 + ch) x 256 threads.
// ---------------------------------------------------------------------------
__global__ __launch_bounds__(256, 2) void k2_kva(
    const float* __restrict__ t1g, const float* __restrict__ Wq2,
    const float* __restrict__ bq2, const float* __restrict__ Wo1,
    float* __restrict__ Ap, float* __restrict__ zg)
{
    __shared__ float kf_c[64][68];
    __shared__ float v_c[64][68];
    __shared__ float aw[4][64][13];   // pad 13: conflict-free perm-order access
    const int t = threadIdx.x;
    const int bi = blockIdx.x;
    const int b = bi >> 6, h = (bi >> 4) & 3, ch = bi & 15;
    const int c = t & 63, wv = t >> 6;

    // hoist k/v weight columns (this head, this c) into registers
    float wkr[24], wvr[24];
    #pragma unroll
    for (int j = 0; j < 24; ++j) {
        wkr[j] = Wq2[j * 768 + 256 + h * 64 + c];
        wvr[j] = Wq2[j * 768 + 512 + h * 64 + c];
    }
    const float bk = bq2[256 + h * 64 + c];
    const float bv = bq2[512 + h * 64 + c];

    const int d0 = (c >> 3) << 3;    // 8x8 output tile per lane
    const int e0 = (c & 7) << 3;
    float acc[8][8] = {};

    const long rowbase = (long)b * 2048 + (long)ch * 128;
    const long zbase = (((long)b * 4 + h) << 11) + ch * 128;

    for (int sub = 0; sub < 2; ++sub) {
        const long r0row = rowbase + sub * 64;
        // generate kf/v for 64 rows: wave wv handles rows {wv + 4i}
        #pragma unroll
        for (int i = 0; i < 16; ++i) {
            const int r = wv + (i << 2);
            const float* t1row = t1g + (r0row + r) * 24;
            float sk = bk, sv = bv;
            #pragma unroll
            for (int j4 = 0; j4 < 24; j4 += 4) {
                float4 tv = *reinterpret_cast<const float4*>(t1row + j4);
                sk = fmaf(tv.x, wkr[j4 + 0], sk); sv = fmaf(tv.x, wvr[j4 + 0], sv);
                sk = fmaf(tv.y, wkr[j4 + 1], sk); sv = fmaf(tv.y, wvr[j4 + 1], sv);
                sk = fmaf(tv.z, wkr[j4 + 2], sk); sv = fmaf(tv.z, wvr[j4 + 2], sv);
                sk = fmaf(tv.w, wkr[j4 + 3], sk); sv = fmaf(tv.w, wvr[j4 + 3], sv);
            }
            kf_c[r][c] = sk > 0.f ? sk + 1.f : __expf(sk);
            v_c[r][c] = sv;
        }
        __syncthreads();
        // z for these 64 rows: wave 0, one row per lane
        if (wv == 0) {
            float rs = 0.f;
            #pragma unroll
            for (int k = 0; k < 16; ++k) {
                float4 kk = *reinterpret_cast<const float4*>(&kf_c[c][k << 2]);
                rs += (kk.x + kk.y) + (kk.z + kk.w);
            }
            zg[zbase + sub * 64 + c] = 1.0f / (rs + 1e-8f);
        }
        // accumulate: wave wv handles n in [wv*16, wv*16+16)
        for (int k = 0; k < 16; ++k) {
            const int n = wv * 16 + k;
            float4 ka0 = *reinterpret_cast<const float4*>(&kf_c[n][d0]);
            float4 ka1 = *reinterpret_cast<const float4*>(&kf_c[n][d0 + 4]);
            float4 va0 = *reinterpret_cast<const float4*>(&v_c[n][e0]);
            float4 va1 = *reinterpret_cast<const float4*>(&v_c[n][e0 + 4]);
            const float ka[8] = {ka0.x, ka0.y, ka0.z, ka0.w, ka1.x, ka1.y, ka1.z, ka1.w};
            const float va[8] = {va0.x, va0.y, va0.z, va0.w, va1.x, va1.y, va1.z, va1.w};
            #pragma unroll
            for (int i = 0; i < 8; ++i) {
                #pragma unroll
                for (int j = 0; j < 8; ++j)
                    acc[i][j] = fmaf(ka[i], va[j], acc[i][j]);
            }
        }
        __syncthreads();
    }

    // per-wave A-partial: pA[i][g] = sum_j acc[i][j] * Wo1[h*64+e0+j][g]
    float pA[8][8] = {};
    #pragma unroll
    for (int j = 0; j < 8; ++j) {
        const float4 wa = *reinterpret_cast<const float4*>(&Wo1[(h * 64 + e0 + j) * 8]);
        const float4 wbv = *reinterpret_cast<const float4*>(&Wo1[(h * 64 + e0 + j) * 8 + 4]);
        const float wg[8] = {wa.x, wa.y, wa.z, wa.w, wbv.x, wbv.y, wbv.z, wbv.w};
        #pragma unroll
        for (int i = 0; i < 8; ++i) {
            #pragma unroll
            for (int g = 0; g < 8; ++g)
                pA[i][g] = fmaf(acc[i][j], wg[g], pA[i][g]);
        }
    }
    // butterfly-sum over the 8 e-groups (lane bits 0..2)
    #pragma unroll
    for (int i = 0; i < 8; ++i) {
        #pragma unroll
        for (int g = 0; g < 8; ++g) {
            float vgl = pA[i][g];
            vgl += __shfl_xor(vgl, 1, 64);
            vgl += __shfl_xor(vgl, 2, 64);
            vgl += __shfl_xor(vgl, 4, 64);
            pA[i][g] = vgl;
        }
    }
    // lane with (c&7)==i writes row d = d0+i at perm index pi = (i<<3)|(c>>3)
    const int kq = c >> 3;
    #pragma unroll
    for (int i = 0; i < 8; ++i) {
        if ((c & 7) == i) {
            const int pi = (i << 3) | kq;
            #pragma unroll
            for (int g = 0; g < 8; ++g) aw[wv][pi][g] = pA[i][g];
        }
    }
    __syncthreads();
    // block-reduce 4 waves; store in perm order o = g*64 + pi
    #pragma unroll
    for (int k = 0; k < 2; ++k) {
        const int o = k * 256 + t;
        const int pi = o & 63, g = o >> 6;
        Ap[(long)bi * 512 + o] = (aw[0][pi][g] + aw[1][pi][g]) +
                                 (aw[2][pi][g] + aw[3][pi][g]);
    }
}

// ---------------------------------------------------------------------------
// K2b: A[b, h*512 + o] = sum over 16 chunks of Ap. grid 64 x 256.
// ---------------------------------------------------------------------------
__global__ __launch_bounds__(256) void k2b_redA(
    const float* __restrict__ Ap, float* __restrict__ Ag)
{
    const int og = blockIdx.x * 256 + threadIdx.x;   // 0..16383
    const int b = og >> 11;
    const int rem = og & 2047;
    const int h = rem >> 9, idx = rem & 511;
    const float* src = Ap + ((long)(b * 64 + h * 16)) * 512 + idx;
    float s = 0.f;
    #pragma unroll
    for (int chk = 0; chk < 16; ++chk) s += src[(long)chk * 512];
    Ag[og] = s;
}

// ---------------------------------------------------------------------------
// K3: out = ((z*qf) @ A) @ Wo2' : 512 blocks x 256 threads, 32 rows/block.
// P1: thread=c, Wq2 column in 24 VGPRs, write z*qf -> LDS [32][260].
// P2: thread=(row,g), o1 = zqf-row . AsT[g] (float4, conflict-free pads).
// P3: thread=e, Wo2 column in 8 VGPRs, coalesced 1KB/row stores.
// ---------------------------------------------------------------------------
__global__ __launch_bounds__(256, 2) void k3_out(
    const float* __restrict__ t1g, const float* __restrict__ Wq2,
    const float* __restrict__ bq2, const float* __restrict__ zg,
    const float* __restrict__ Ag,
    const float* __restrict__ bo1, const float* __restrict__ Wo2,
    const float* __restrict__ bo2, float* __restrict__ outg)
{
    __shared__ __align__(16) float t1s[768];        // [32][24]
    __shared__ __align__(16) float zqf[32 * 260];
    __shared__ __align__(16) float AsT[8 * 264];    // [g][c]
    __shared__ __align__(16) float o1s[256];        // [32][8]
    const int t = threadIdx.x;
    const long row0 = (long)blockIdx.x * 32;
    const int b = (int)(row0 >> 11);

    // stage t1 rows (768 floats, coalesced float4)
    if (t < 192) {
        float4 v4 = *reinterpret_cast<const float4*>(&t1g[row0 * 24 + t * 4]);
        t1s[t * 4 + 0] = v4.x; t1s[t * 4 + 1] = v4.y;
        t1s[t * 4 + 2] = v4.z; t1s[t * 4 + 3] = v4.w;
    }
    // stage A (un-permute: o = h*512 + g*64 + pi, d = ((pi&7)<<3)|(pi>>3))
    #pragma unroll
    for (int kk = 0; kk < 8; ++kk) {
        const int o = kk * 256 + t;
        const float val = Ag[(long)b * 2048 + o];
        const int hh = o >> 9;
        const int rem = o & 511;
        const int g = rem >> 6, pi = rem & 63;
        const int d = ((pi & 7) << 3) | (pi >> 3);
        AsT[g * 264 + hh * 64 + d] = val;
    }
    // hoisted weights for P1
    float wqr[24];
    #pragma unroll
    for (int j = 0; j < 24; ++j) wqr[j] = Wq2[j * 768 + t];
    const float bqc = bq2[t];
    const int h1 = t >> 6;
    const long zb = (((long)b * 4 + h1) << 11) + (row0 & 2047);
    __syncthreads();

    // P1: zqf[r][c] for 32 rows
    for (int r = 0; r < 32; ++r) {
        float q0 = bqc;
        #pragma unroll
        for (int j4 = 0; j4 < 24; j4 += 4) {
            float4 tv = *reinterpret_cast<const float4*>(&t1s[r * 24 + j4]);
            q0 = fmaf(tv.x, wqr[j4 + 0], q0);
            q0 = fmaf(tv.y, wqr[j4 + 1], q0);
            q0 = fmaf(tv.z, wqr[j4 + 2], q0);
            q0 = fmaf(tv.w, wqr[j4 + 3], q0);
        }
        const float qf = q0 > 0.f ? q0 + 1.f : __expf(q0);
        zqf[r * 260 + t] = qf * zg[zb + r];
    }
    __syncthreads();

    // P2: o1[row][g] = sum_c zqf[row][c] * AsT[g][c]  (+bo1)
    {
        const int row = t >> 3, g = t & 7;
        float s = 0.f;
        #pragma unroll 8
        for (int c4 = 0; c4 < 256; c4 += 4) {
            float4 zq = *reinterpret_cast<const float4*>(&zqf[row * 260 + c4]);
            float4 av = *reinterpret_cast<const float4*>(&AsT[g * 264 + c4]);
            s = fmaf(zq.x, av.x, s);
            s = fmaf(zq.y, av.y, s);
            s = fmaf(zq.z, av.z, s);
            s = fmaf(zq.w, av.w, s);
        }
        o1s[t] = s + bo1[g];
    }
    __syncthreads();

    // P3: out[row][e] = bo2[e] + o1[row][:] . Wo2[:,e]
    float wo2r[8];
    #pragma unroll
    for (int j = 0; j < 8; ++j) wo2r[j] = Wo2[j * 256 + t];
    const float bo2e = bo2[t];
    for (int r = 0; r < 32; ++r) {
        const float4 oa = *reinterpret_cast<const float4*>(&o1s[r * 8]);
        const float4 ob = *reinterpret_cast<const float4*>(&o1s[r * 8 + 4]);
        float vv = bo2e;
        vv = fmaf(oa.x, wo2r[0], vv); vv = fmaf(oa.y, wo2r[1], vv);
        vv = fmaf(oa.z, wo2r[2], vv); vv = fmaf(oa.w, wo2r[3], vv);
        vv = fmaf(ob.x, wo2r[4], vv); vv = fmaf(ob.y, wo2r[5], vv);
        vv = fmaf(ob.z, wo2r[6], vv); vv = fmaf(ob.w, wo2r[7], vv);
        outg[(row0 + r) * 256 + t] = vv;
    }
}

// ---------------------------------------------------------------------------
extern "C" void kernel_launch(void* const* d_in, const int* in_sizes, int n_in,
                              void* d_out, int out_size, void* d_ws, size_t ws_size,
                              hipStream_t stream)
{
    const float* x    = (const float*)d_in[0];
    const float* Wq1  = (const float*)d_in[1];
    const float* bq1  = (const float*)d_in[2];
    const float* Wq2  = (const float*)d_in[3];
    const float* bq2  = (const float*)d_in[4];
    const float* Wo1  = (const float*)d_in[5];
    const float* bo1  = (const float*)d_in[6];
    const float* Wo2  = (const float*)d_in[7];
    const float* bo2  = (const float*)d_in[8];
    // d_in[9] = gu, d_in[10] = gv : unused (reg-loss collapses analytically)
    const float* logw = (const float*)d_in[11];

    float* out = (float*)d_out;            // [8,2048,256] f32 + loss scalar
    float* ws  = (float*)d_ws;
    float* t1g = ws + OFF_T1;
    float* zg  = ws + OFF_Z;
    float* Apg = ws + OFF_AP;
    float* Agg = ws + OFF_A;
    float* WTg = ws + OFF_WT;

    k0_prep<<<1, 256, 0, stream>>>(Wq1, logw, WTg, out + 4194304);
    k1_t1<<<256, 128, 0, stream>>>(x, WTg, bq1, t1g);
    k2_kva<<<512, 256, 0, stream>>>(t1g, Wq2, bq2, Wo1, Apg, zg);
    k2b_redA<<<64, 256, 0, stream>>>(Apg, Agg);
    k3_out<<<512, 256, 0, stream>>>(t1g, Wq2, bq2, zg, Agg,
                                    bo1, Wo2, bo2, out);
}

// Round 3
// 49.100 us; speedup vs baseline: 2.0193x; 1.4775x over previous
//
#include <hip/hip_runtime.h>
#include <hip/hip_bf16.h>

// B=8, N=2048, H=256, HEADS=4, hd=64, BNECK=8 (TB=24, 3H=768)
// attn_reg_loss = exp(log_w)/N exactly (softmax rows sum to 1) -> gu/gv dead.
// WvA-trick: v is linear in t1, so vA[n][g] = v[n,:]@Wo1_h = t1[n,:]@WvA_h + bvA_h
// with WvA_h = Wv_h @ Wo1_h ([24][8] per head). v and kv never materialize:
//   A_h[d][g] = sum_n kf[n][d] * vA[n][g];  o1 = (z*qf) @ A;  out = o1 @ Wo2.
//
// ws layout (floats):
//   t1  : 0       .. 393216   [16384][24]
//   z   : 393216  .. 458752   [8][4][2048]
//   Ap  : 458752  .. 983040   [1024 blocks][512]  per-chunk A partials (d*8+g)
//   A   : 983040  .. 999424   [8][2048]           (b, h*512 + d*8 + g)
//   WvA : 999424  .. 1000224  [4][24][8] + bvA[4][8] at +768

#define OFF_T1  0
#define OFF_Z   393216
#define OFF_AP  458752
#define OFF_A   983040
#define OFF_WVA 999424

// ---------------------------------------------------------------------------
// K1: t1 = x @ Wq1 + bq1  ([16384 x 256] * [256 x 24]); 512 blocks x 128 thr,
// 32 rows/block, 2r x 3j register tile, conflict-free padded LDS.
// Blocks 0..3 additionally compute WvA/bvA for head=bid; block 0 writes loss.
// ---------------------------------------------------------------------------
__global__ __launch_bounds__(128) void k1_t1(
    const float* __restrict__ x, const float* __restrict__ Wq1,
    const float* __restrict__ bq1, const float* __restrict__ Wq2,
    const float* __restrict__ bq2, const float* __restrict__ Wo1,
    const float* __restrict__ logw,
    float* __restrict__ t1g, float* __restrict__ WvAg,
    float* __restrict__ loss_out)
{
    __shared__ float xs[32][260];
    __shared__ float w1t[24][260];
    const int t = threadIdx.x;
    const int bid = blockIdx.x;
    const long row0 = (long)bid * 32;

    {   // stage x (32 x 256) via float4
        const float4* xg4 = reinterpret_cast<const float4*>(x + row0 * 256);
        #pragma unroll
        for (int i = 0; i < 16; ++i) {
            const int idx = t + i * 128;
            float4 v4 = xg4[idx];
            const int r = idx >> 6, c4 = (idx & 63) << 2;
            xs[r][c4 + 0] = v4.x; xs[r][c4 + 1] = v4.y;
            xs[r][c4 + 2] = v4.z; xs[r][c4 + 3] = v4.w;
        }
    }
    // stage Wq1 transposed: w1t[j][i] = Wq1[i*24+j]
    for (int i = t; i < 6144; i += 128) {
        const int ii = i / 24, j = i - ii * 24;
        w1t[j][ii] = Wq1[i];
    }
    __syncthreads();

    const int rgrp = t >> 3;      // 0..15
    const int jgrp = t & 7;       // 0..7
    float acc[2][3] = {};
    for (int i4 = 0; i4 < 64; ++i4) {
        float4 xa[2], wb[3];
        #pragma unroll
        for (int rr = 0; rr < 2; ++rr)
            xa[rr] = *reinterpret_cast<const float4*>(&xs[rgrp + 16 * rr][i4 << 2]);
        #pragma unroll
        for (int jj = 0; jj < 3; ++jj)
            wb[jj] = *reinterpret_cast<const float4*>(&w1t[jgrp + 8 * jj][i4 << 2]);
        #pragma unroll
        for (int rr = 0; rr < 2; ++rr) {
            #pragma unroll
            for (int jj = 0; jj < 3; ++jj) {
                acc[rr][jj] = fmaf(xa[rr].x, wb[jj].x, acc[rr][jj]);
                acc[rr][jj] = fmaf(xa[rr].y, wb[jj].y, acc[rr][jj]);
                acc[rr][jj] = fmaf(xa[rr].z, wb[jj].z, acc[rr][jj]);
                acc[rr][jj] = fmaf(xa[rr].w, wb[jj].w, acc[rr][jj]);
            }
        }
    }
    #pragma unroll
    for (int rr = 0; rr < 2; ++rr) {
        #pragma unroll
        for (int jj = 0; jj < 3; ++jj) {
            const int j = jgrp + 8 * jj;
            t1g[(row0 + rgrp + 16 * rr) * 24 + j] = acc[rr][jj] + bq1[j];
        }
    }

    // WvA_h = Wv_h @ Wo1_h  (+ bvA_h) for head = bid (blocks 0..3)
    if (bid < 4) {
        const int h = bid;
        for (int o = t; o < 200; o += 128) {
            float s = 0.f;
            if (o < 192) {
                const int j = o >> 3, g = o & 7;
                const float* wv2 = Wq2 + j * 768 + 512 + h * 64;
                const float* wo  = Wo1 + (h * 64) * 8 + g;
                #pragma unroll 8
                for (int e = 0; e < 64; ++e) s = fmaf(wv2[e], wo[e * 8], s);
                WvAg[h * 192 + o] = s;
            } else {
                const int g = o - 192;
                const float* bv = bq2 + 512 + h * 64;
                const float* wo = Wo1 + (h * 64) * 8 + g;
                #pragma unroll 8
                for (int e = 0; e < 64; ++e) s = fmaf(bv[e], wo[e * 8], s);
                WvAg[768 + h * 8 + g] = s;
            }
        }
        if (bid == 0 && t == 0)
            loss_out[0] = __expf(logw[0]) * (1.0f / 2048.0f);
    }
}

// ---------------------------------------------------------------------------
// K2: per (b, h, chunk of 64 rows): gen kf from t1, gen vA = t1@WvA + bvA,
// accumulate A-partial[d][g] += kf[n][d]*vA[n][g]; z = 1/(sum_d kf + 1e-8).
// grid 1024 blocks (b*128 + h*32 + ch) x 256 threads. ~29 KB LDS, acc[8].
// ---------------------------------------------------------------------------
__global__ __launch_bounds__(256) void k2_kva(
    const float* __restrict__ t1g, const float* __restrict__ Wq2,
    const float* __restrict__ bq2, const float* __restrict__ WvAg,
    float* __restrict__ Ap, float* __restrict__ zg)
{
    __shared__ float kf_c[64][68];
    __shared__ float vA_s[64][8];
    __shared__ float aw[4][64][9];
    const int t = threadIdx.x;
    const int bi = blockIdx.x;
    const int b = bi >> 7, h = (bi >> 5) & 3, ch = bi & 31;
    const int c = t & 63, wv = t >> 6, g8 = t & 7;

    // hoist weights: k-column (this c) and WvA-column (g = g8)
    float wkr[24], wva[24];
    #pragma unroll
    for (int j = 0; j < 24; ++j) {
        wkr[j] = Wq2[j * 768 + 256 + h * 64 + c];
        wva[j] = WvAg[h * 192 + j * 8 + g8];
    }
    const float bk  = bq2[256 + h * 64 + c];
    const float bva = WvAg[768 + h * 8 + g8];

    const long r0row = (long)b * 2048 + (long)ch * 64;

    // gen kf: wave wv handles rows {wv + 4i}, lane = column c
    #pragma unroll
    for (int i = 0; i < 16; ++i) {
        const int r = wv + (i << 2);
        const float* t1row = t1g + (r0row + r) * 24;
        float sk = bk;
        #pragma unroll
        for (int j4 = 0; j4 < 24; j4 += 4) {
            float4 tv = *reinterpret_cast<const float4*>(t1row + j4);
            sk = fmaf(tv.x, wkr[j4 + 0], sk);
            sk = fmaf(tv.y, wkr[j4 + 1], sk);
            sk = fmaf(tv.z, wkr[j4 + 2], sk);
            sk = fmaf(tv.w, wkr[j4 + 3], sk);
        }
        kf_c[r][c] = sk > 0.f ? sk + 1.f : __expf(sk);
    }
    // gen vA: 512 outputs, 2 per thread (n = o>>3, g = g8)
    #pragma unroll
    for (int p = 0; p < 2; ++p) {
        const int o = t + p * 256;
        const int n = o >> 3;
        const float* t1row = t1g + (r0row + n) * 24;
        float s = bva;
        #pragma unroll
        for (int j4 = 0; j4 < 24; j4 += 4) {
            float4 tv = *reinterpret_cast<const float4*>(t1row + j4);
            s = fmaf(tv.x, wva[j4 + 0], s);
            s = fmaf(tv.y, wva[j4 + 1], s);
            s = fmaf(tv.z, wva[j4 + 2], s);
            s = fmaf(tv.w, wva[j4 + 3], s);
        }
        vA_s[n][g8] = s;
    }
    __syncthreads();

    // z: each wave handles 16 rows (lanes 0..15 only)
    if (c < 16) {
        const int row = wv * 16 + c;
        float rs = 0.f;
        #pragma unroll
        for (int k = 0; k < 16; ++k) {
            float4 kk = *reinterpret_cast<const float4*>(&kf_c[row][k << 2]);
            rs += (kk.x + kk.y) + (kk.z + kk.w);
        }
        zg[(((long)b * 4 + h) << 11) + ch * 64 + row] = 1.0f / (rs + 1e-8f);
    }

    // A-acc: wave wv handles n in [wv*16, wv*16+16), lane = d = c
    float acc[8] = {};
    #pragma unroll
    for (int k = 0; k < 16; ++k) {
        const int n = wv * 16 + k;
        const float kfv = kf_c[n][c];
        const float4 va0 = *reinterpret_cast<const float4*>(&vA_s[n][0]);
        const float4 va1 = *reinterpret_cast<const float4*>(&vA_s[n][4]);
        acc[0] = fmaf(kfv, va0.x, acc[0]); acc[1] = fmaf(kfv, va0.y, acc[1]);
        acc[2] = fmaf(kfv, va0.z, acc[2]); acc[3] = fmaf(kfv, va0.w, acc[3]);
        acc[4] = fmaf(kfv, va1.x, acc[4]); acc[5] = fmaf(kfv, va1.y, acc[5]);
        acc[6] = fmaf(kfv, va1.z, acc[6]); acc[7] = fmaf(kfv, va1.w, acc[7]);
    }
    #pragma unroll
    for (int g = 0; g < 8; ++g) aw[wv][c][g] = acc[g];
    __syncthreads();

    // block-reduce 4 wave partials; Ap order o = d*8 + g (natural)
    #pragma unroll
    for (int p = 0; p < 2; ++p) {
        const int o = t + p * 256;
        const int d = o >> 3, g = o & 7;
        Ap[(long)bi * 512 + o] = (aw[0][d][g] + aw[1][d][g]) +
                                 (aw[2][d][g] + aw[3][d][g]);
    }
}

// ---------------------------------------------------------------------------
// K2b: A[b, h*512 + o] = sum over 32 chunks of Ap. grid 64 x 256.
// ---------------------------------------------------------------------------
__global__ __launch_bounds__(256) void k2b_redA(
    const float* __restrict__ Ap, float* __restrict__ Ag)
{
    const int og = blockIdx.x * 256 + threadIdx.x;   // 0..16383
    const int b = og >> 11;
    const int rem = og & 2047;
    const int h = rem >> 9, idx = rem & 511;
    const float* src = Ap + ((long)(b * 128 + h * 32)) * 512 + idx;
    float s = 0.f;
    #pragma unroll
    for (int chk = 0; chk < 32; ++chk) s += src[(long)chk * 512];
    Ag[og] = s;
}

// ---------------------------------------------------------------------------
// K3: out = ((z*qf) @ A) @ Wo2' : 512 blocks x 256 threads, 32 rows/block.
// P1: thread=c, Wq2 q-column in 24 VGPRs, write z*qf -> LDS.
// P2: thread=(row,g), o1 = zqf-row . AsT[g] (broadcast b128, conflict-free).
// P3: thread=e, Wo2 column in 8 VGPRs, coalesced stores.
// ---------------------------------------------------------------------------
__global__ __launch_bounds__(256) void k3_out(
    const float* __restrict__ t1g, const float* __restrict__ Wq2,
    const float* __restrict__ bq2, const float* __restrict__ zg,
    const float* __restrict__ Ag,
    const float* __restrict__ bo1, const float* __restrict__ Wo2,
    const float* __restrict__ bo2, float* __restrict__ outg)
{
    __shared__ __align__(16) float t1s[768];        // [32][24]
    __shared__ __align__(16) float zqf[32 * 260];
    __shared__ __align__(16) float AsT[8 * 264];    // [g][h*64+d]
    __shared__ __align__(16) float o1s[256];        // [32][8]
    const int t = threadIdx.x;
    const long row0 = (long)blockIdx.x * 32;
    const int b = (int)(row0 >> 11);

    // stage t1 rows (768 floats, coalesced float4)
    if (t < 192) {
        float4 v4 = *reinterpret_cast<const float4*>(&t1g[row0 * 24 + t * 4]);
        t1s[t * 4 + 0] = v4.x; t1s[t * 4 + 1] = v4.y;
        t1s[t * 4 + 2] = v4.z; t1s[t * 4 + 3] = v4.w;
    }
    // stage A transposed: o = h*512 + d*8 + g -> AsT[g][h*64+d]
    #pragma unroll
    for (int kk = 0; kk < 8; ++kk) {
        const int o = kk * 256 + t;
        const float val = Ag[(long)b * 2048 + o];
        const int hh = o >> 9, d = (o >> 3) & 63, g = o & 7;
        AsT[g * 264 + hh * 64 + d] = val;
    }
    // hoisted weights for P1 (q block = first 256 cols of Wq2)
    float wqr[24];
    #pragma unroll
    for (int j = 0; j < 24; ++j) wqr[j] = Wq2[j * 768 + t];
    const float bqc = bq2[t];
    const int h1 = t >> 6;
    const long zb = (((long)b * 4 + h1) << 11) + (row0 & 2047);
    __syncthreads();

    // P1: zqf[r][c] for 32 rows
    for (int r = 0; r < 32; ++r) {
        float q0 = bqc;
        #pragma unroll
        for (int j4 = 0; j4 < 24; j4 += 4) {
            float4 tv = *reinterpret_cast<const float4*>(&t1s[r * 24 + j4]);
            q0 = fmaf(tv.x, wqr[j4 + 0], q0);
            q0 = fmaf(tv.y, wqr[j4 + 1], q0);
            q0 = fmaf(tv.z, wqr[j4 + 2], q0);
            q0 = fmaf(tv.w, wqr[j4 + 3], q0);
        }
        const float qf = q0 > 0.f ? q0 + 1.f : __expf(q0);
        zqf[r * 260 + t] = qf * zg[zb + r];
    }
    __syncthreads();

    // P2: o1[row][g] = sum_c zqf[row][c] * AsT[g][c]  (+bo1)
    {
        const int row = t >> 3, g = t & 7;
        float s = 0.f;
        #pragma unroll 8
        for (int c4 = 0; c4 < 256; c4 += 4) {
            float4 zq = *reinterpret_cast<const float4*>(&zqf[row * 260 + c4]);
            float4 av = *reinterpret_cast<const float4*>(&AsT[g * 264 + c4]);
            s = fmaf(zq.x, av.x, s);
            s = fmaf(zq.y, av.y, s);
            s = fmaf(zq.z, av.z, s);
            s = fmaf(zq.w, av.w, s);
        }
        o1s[t] = s + bo1[g];
    }
    __syncthreads();

    // P3: out[row][e] = bo2[e] + o1[row][:] . Wo2[:,e]
    float wo2r[8];
    #pragma unroll
    for (int j = 0; j < 8; ++j) wo2r[j] = Wo2[j * 256 + t];
    const float bo2e = bo2[t];
    for (int r = 0; r < 32; ++r) {
        const float4 oa = *reinterpret_cast<const float4*>(&o1s[r * 8]);
        const float4 ob = *reinterpret_cast<const float4*>(&o1s[r * 8 + 4]);
        float vv = bo2e;
        vv = fmaf(oa.x, wo2r[0], vv); vv = fmaf(oa.y, wo2r[1], vv);
        vv = fmaf(oa.z, wo2r[2], vv); vv = fmaf(oa.w, wo2r[3], vv);
        vv = fmaf(ob.x, wo2r[4], vv); vv = fmaf(ob.y, wo2r[5], vv);
        vv = fmaf(ob.z, wo2r[6], vv); vv = fmaf(ob.w, wo2r[7], vv);
        outg[(row0 + r) * 256 + t] = vv;
    }
}

// ---------------------------------------------------------------------------
extern "C" void kernel_launch(void* const* d_in, const int* in_sizes, int n_in,
                              void* d_out, int out_size, void* d_ws, size_t ws_size,
                              hipStream_t stream)
{
    const float* x    = (const float*)d_in[0];
    const float* Wq1  = (const float*)d_in[1];
    const float* bq1  = (const float*)d_in[2];
    const float* Wq2  = (const float*)d_in[3];
    const float* bq2  = (const float*)d_in[4];
    const float* Wo1  = (const float*)d_in[5];
    const float* bo1  = (const float*)d_in[6];
    const float* Wo2  = (const float*)d_in[7];
    const float* bo2  = (const float*)d_in[8];
    // d_in[9] = gu, d_in[10] = gv : unused (reg-loss collapses analytically)
    const float* logw = (const float*)d_in[11];

    float* out = (float*)d_out;            // [8,2048,256] f32 + loss scalar
    float* ws  = (float*)d_ws;
    float* t1g  = ws + OFF_T1;
    float* zg   = ws + OFF_Z;
    float* Apg  = ws + OFF_AP;
    float* Agg  = ws + OFF_A;
    float* WvAg = ws + OFF_WVA;

    k1_t1<<<512, 128, 0, stream>>>(x, Wq1, bq1, Wq2, bq2, Wo1, logw,
                                   t1g, WvAg, out + 4194304);
    k2_kva<<<1024, 256, 0, stream>>>(t1g, Wq2, bq2, WvAg, Apg, zg);
    k2b_redA<<<64, 256, 0, stream>>>(Apg, Agg);
    k3_out<<<512, 256, 0, stream>>>(t1g, Wq2, bq2, zg, Agg,
                                    bo1, Wo2, bo2, out);
}